// Round 1
// baseline (75.283 us; speedup 1.0000x reference)
//
#include <hip/hip_runtime.h>
#include <math.h>

#define H 768
#define ISZ 512
#define IN1 513   // I+1
#define NARM 32
#define NU_C 0.1f

// U region offsets (elements)
#define U_WIH 0
#define U_WHH (3072*513)                 // 1575936
#define U_BIH (U_WHH + 3072*768)         // 3935232
#define U_BHH (U_BIH + 3072)             // 3938304
#define U_FCW (U_BHH + 3072)             // 3941376
#define U_FCB (U_FCW + 32*768)           // 3965952

// out offsets (elements)
#define O_SELR 0
#define O_PROB 1
#define O_SELA 33
#define O_HN   34
#define O_CN   (34+768)
#define O_U    (34+768+768)   // 1570

// ws layout (float units)
#define W_D    0        // 4*768 D factors (gate-major)
#define W_T    3072     // 3072 per-row U sums
#define W_HN   6144     // 768 h_new
#define W_SEL  6912     // 1 int

__device__ inline float wave_reduce(float v) {
    for (int d = 32; d > 0; d >>= 1) v += __shfl_xor(v, d, 64);
    return v;
}

// Kernel A: gates GEMV + activations + D factors. 192 blocks x 256 (wave per j).
__global__ __launch_bounds__(256) void k_gates(
    const float* __restrict__ x, const float* __restrict__ prevr,
    const float* __restrict__ h0, const float* __restrict__ c0,
    const float* __restrict__ Wih, const float* __restrict__ Whh,
    const float* __restrict__ bih, const float* __restrict__ bhh,
    float* __restrict__ out, float* __restrict__ ws)
{
    int wave = threadIdx.x >> 6;
    int lane = threadIdx.x & 63;
    int j = blockIdx.x * 4 + wave;  // 0..767
    float a0 = 0.f, a1 = 0.f, a2 = 0.f, a3 = 0.f;
    const float pr = prevr[0];
    const float* r0 = Wih + (size_t)(0*H + j) * IN1;
    const float* r1 = Wih + (size_t)(1*H + j) * IN1;
    const float* r2 = Wih + (size_t)(2*H + j) * IN1;
    const float* r3 = Wih + (size_t)(3*H + j) * IN1;
    for (int k = lane; k < IN1; k += 64) {
        float xv = (k < ISZ) ? x[k] : pr;
        a0 += r0[k] * xv; a1 += r1[k] * xv; a2 += r2[k] * xv; a3 += r3[k] * xv;
    }
    const float* s0 = Whh + (size_t)(0*H + j) * H;
    const float* s1 = Whh + (size_t)(1*H + j) * H;
    const float* s2 = Whh + (size_t)(2*H + j) * H;
    const float* s3 = Whh + (size_t)(3*H + j) * H;
    for (int k = lane; k < H; k += 64) {
        float hv = h0[k];
        a0 += s0[k] * hv; a1 += s1[k] * hv; a2 += s2[k] * hv; a3 += s3[k] * hv;
    }
    a0 = wave_reduce(a0); a1 = wave_reduce(a1);
    a2 = wave_reduce(a2); a3 = wave_reduce(a3);
    if (lane == 0) {
        float zi = a0 + bih[0*H + j] + bhh[0*H + j];
        float zf = a1 + bih[1*H + j] + bhh[1*H + j];
        float zg = a2 + bih[2*H + j] + bhh[2*H + j];
        float zo = a3 + bih[3*H + j] + bhh[3*H + j];
        float ig = 1.f / (1.f + expf(-zi));
        float fg = 1.f / (1.f + expf(-zf));
        float gg = tanhf(zg);
        float og = 1.f / (1.f + expf(-zo));
        float cj = c0[j];
        float cn = fg * cj + ig * gg;
        float t  = tanhf(cn);
        float hn = og * t;
        float dtc = og * (1.f - t * t);
        ws[W_D + 0*H + j] = dtc * gg * ig * (1.f - ig);
        ws[W_D + 1*H + j] = dtc * cj * fg * (1.f - fg);
        ws[W_D + 2*H + j] = dtc * ig * (1.f - gg * gg);
        ws[W_D + 3*H + j] = t * og * (1.f - og);
        ws[W_HN + j] = hn;
        out[O_HN + j] = hn;
        out[O_CN + j] = cn;
    }
}

// Kernel C: per-row reciprocal-U weighted sums. 768 blocks x 256 (wave per row).
__global__ __launch_bounds__(256) void k_rowsum(
    const float* __restrict__ x, const float* __restrict__ prevr,
    const float* __restrict__ h0, const float* __restrict__ U,
    float* __restrict__ ws)
{
    int wave = threadIdx.x >> 6;
    int lane = threadIdx.x & 63;
    int r = blockIdx.x * 4 + wave;  // 0..3071
    const float pr = prevr[0];
    const float* uih = U + U_WIH + (size_t)r * IN1;
    const float* uhh = U + U_WHH + (size_t)r * H;
    float acc = 0.f;
    for (int k = lane; k < IN1; k += 64) {
        float xv = (k < ISZ) ? x[k] : pr;
        acc += xv * xv / uih[k];
    }
    for (int k = lane; k < H; k += 64) {
        float hv = h0[k];
        acc += hv * hv / uhh[k];
    }
    acc = wave_reduce(acc);
    if (lane == 0)
        ws[W_T + r] = acc + 1.f / U[U_BIH + r] + 1.f / U[U_BHH + r];
}

// Kernel D: arm scores, UCB argmax, softmax, small outputs. 1 block x 256.
__global__ __launch_bounds__(256) void k_select(
    const float* __restrict__ fcW, const float* __restrict__ fcb,
    const float* __restrict__ U, float* __restrict__ out, float* __restrict__ ws)
{
    __shared__ float wsum_s[H];
    __shared__ float hn_s[H];
    __shared__ float red_r[NARM], red_s[NARM], red_q[NARM];
    int t = threadIdx.x;
    for (int j = t; j < H; j += 256) {
        float d0 = ws[W_D + 0*H + j], T0 = ws[W_T + 0*H + j];
        float d1 = ws[W_D + 1*H + j], T1 = ws[W_T + 1*H + j];
        float d2 = ws[W_D + 2*H + j], T2 = ws[W_T + 2*H + j];
        float d3 = ws[W_D + 3*H + j], T3 = ws[W_T + 3*H + j];
        wsum_s[j] = d0*d0*T0 + d1*d1*T1 + d2*d2*T2 + d3*d3*T3;
        hn_s[j] = ws[W_HN + j];
    }
    __syncthreads();
    int wave = t >> 6, lane = t & 63;
    for (int a = wave; a < NARM; a += 4) {
        float ar = 0.f, as = 0.f, aq = 0.f;
        const float* frow = fcW + (size_t)a * H;
        const float* urow = U + U_FCW + (size_t)a * H;
        for (int j = lane; j < H; j += 64) {
            float fw = frow[j], hv = hn_s[j];
            ar += fw * hv;
            as += fw * fw * wsum_s[j];
            aq += hv * hv / urow[j];
        }
        ar = wave_reduce(ar); as = wave_reduce(as); aq = wave_reduce(aq);
        if (lane == 0) {
            red_r[a] = ar + fcb[a];
            red_s[a] = as;
            red_q[a] = aq + 1.f / U[U_FCB + a];
        }
    }
    __syncthreads();
    if (t == 0) {
        float cum = 0.f, best = -1e30f;
        int sel = 0;
        for (int a = 0; a < NARM; a++) {
            cum += red_q[a];
            float sig = sqrtf(red_s[a] + cum);
            float sc = red_r[a] + NU_C * sig;
            if (sc > best) { best = sc; sel = a; }
        }
        float mx = -1e30f;
        for (int a = 0; a < NARM; a++) mx = fmaxf(mx, red_r[a]);
        float se = 0.f, e[NARM];
        for (int a = 0; a < NARM; a++) { e[a] = expf(red_r[a] - mx); se += e[a]; }
        float inv = 1.f / se;
        for (int a = 0; a < NARM; a++) out[O_PROB + a] = e[a] * inv;
        out[O_SELR] = red_r[sel];
        out[O_SELA] = (float)sel;
        ((int*)ws)[W_SEL] = sel;
    }
}

// Kernel E: U_new = U + G[sel]^2, region-wise. 6265 blocks x 256.
__global__ __launch_bounds__(256) void k_unew(
    const float* __restrict__ x, const float* __restrict__ prevr,
    const float* __restrict__ h0, const float* __restrict__ fcW,
    const float* __restrict__ U, float* __restrict__ out,
    const float* __restrict__ ws)
{
    const int sel = ((const int*)ws)[W_SEL];
    int b = blockIdx.x, t = threadIdx.x;
    float* Un = out + O_U;
    if (b < 3072) {               // W_ih rows
        int r = b;
        int g = r / H, j = r - g * H;
        float s = fcW[(size_t)sel * H + j] * ws[W_D + g*H + j];
        float s2 = s * s;
        const float pr = prevr[0];
        const float* u = U + U_WIH + (size_t)r * IN1;
        float* o = Un + U_WIH + (size_t)r * IN1;
        for (int k = t; k < IN1; k += 256) {
            float xv = (k < ISZ) ? x[k] : pr;
            o[k] = u[k] + s2 * xv * xv;
        }
    } else if (b < 6144) {        // W_hh rows
        int r = b - 3072;
        int g = r / H, j = r - g * H;
        float s = fcW[(size_t)sel * H + j] * ws[W_D + g*H + j];
        float s2 = s * s;
        const float* u = U + U_WHH + (size_t)r * H;
        float* o = Un + U_WHH + (size_t)r * H;
        for (int k = t; k < H; k += 256) {
            float hv = h0[k];
            o[k] = u[k] + s2 * hv * hv;
        }
    } else if (b < 6168) {        // biases (b_ih then b_hh, 6144 elems, 24 blocks)
        int m = (b - 6144) * 256 + t;      // 0..6143
        int r = (m < 3072) ? m : (m - 3072);
        int g = r / H, j = r - g * H;
        float s = fcW[(size_t)sel * H + j] * ws[W_D + g*H + j];
        int idx = U_BIH + m;
        Un[idx] = U[idx] + s * s;
    } else if (b < 6264) {        // fc_W (24576 elems, 96 blocks; 3 blocks per arm row)
        int bb = b - 6168;
        int a = bb / 3;
        int j = (bb - a * 3) * 256 + t;
        float hv = ws[W_HN + j];
        float add = (a <= sel) ? hv * hv : 0.f;
        int e = a * H + j;
        Un[U_FCW + e] = U[U_FCW + e] + add;
    } else {                      // fc_b (32 elems)
        if (t < NARM)
            Un[U_FCB + t] = U[U_FCB + t] + ((t <= sel) ? 1.f : 0.f);
    }
}

extern "C" void kernel_launch(void* const* d_in, const int* in_sizes, int n_in,
                              void* d_out, int out_size, void* d_ws, size_t ws_size,
                              hipStream_t stream) {
    const float* x     = (const float*)d_in[0];
    const float* prevr = (const float*)d_in[1];
    const float* h0    = (const float*)d_in[2];
    const float* c0    = (const float*)d_in[3];
    const float* Wih   = (const float*)d_in[4];
    const float* Whh   = (const float*)d_in[5];
    const float* bih   = (const float*)d_in[6];
    const float* bhh   = (const float*)d_in[7];
    const float* fcW   = (const float*)d_in[8];
    const float* fcb   = (const float*)d_in[9];
    const float* U     = (const float*)d_in[10];
    float* out = (float*)d_out;
    float* ws  = (float*)d_ws;

    hipLaunchKernelGGL(k_gates, dim3(192), dim3(256), 0, stream,
                       x, prevr, h0, c0, Wih, Whh, bih, bhh, out, ws);
    hipLaunchKernelGGL(k_rowsum, dim3(768), dim3(256), 0, stream,
                       x, prevr, h0, U, ws);
    hipLaunchKernelGGL(k_select, dim3(1), dim3(256), 0, stream,
                       fcW, fcb, U, out, ws);
    hipLaunchKernelGGL(k_unew, dim3(6265), dim3(256), 0, stream,
                       x, prevr, h0, fcW, U, out, ws);
}

// Round 2
// 30.872 us; speedup vs baseline: 2.4385x; 2.4385x over previous
//
#include <hip/hip_runtime.h>
#include <math.h>

#define H 768
#define ISZ 512
#define IN1 513   // I+1
#define NARM 32
#define NU_C 0.1f

// U region offsets (elements)
#define U_WIH 0
#define U_WHH (3072*513)                 // 1575936
#define U_BIH (U_WHH + 3072*768)         // 3935232
#define U_BHH (U_BIH + 3072)             // 3938304
#define U_FCW (U_BHH + 3072)             // 3941376
#define U_FCB (U_FCW + 32*768)           // 3965952

// out offsets (elements)
#define O_SELR 0
#define O_PROB 1
#define O_SELA 33
#define O_HN   34
#define O_CN   (34+768)
#define O_U    (34+768+768)   // 1570

// ws layout (float units)
#define W_D    0        // 4*768 D factors (gate-major)
#define W_T    3072     // 3072 per-row U sums
#define W_HN   6144     // 768 h_new
#define W_SEL  6912     // 1 int
#define W_R    7000     // 32 arm rewards
#define W_S    7040     // 32 arm lstm-sigma2
#define W_Q    7080     // 32 arm fc q terms

__device__ inline float wave_reduce(float v) {
    for (int d = 32; d > 0; d >>= 1) v += __shfl_xor(v, d, 64);
    return v;
}

// Kernel PREP: blocks 0..191 -> gates GEMV + activations + D factors (wave per j)
//              blocks 192..959 -> per-row reciprocal-U sums (wave per row)
__global__ __launch_bounds__(256) void k_prep(
    const float* __restrict__ x, const float* __restrict__ prevr,
    const float* __restrict__ h0, const float* __restrict__ c0,
    const float* __restrict__ Wih, const float* __restrict__ Whh,
    const float* __restrict__ bih, const float* __restrict__ bhh,
    const float* __restrict__ U,
    float* __restrict__ out, float* __restrict__ ws)
{
    int wave = threadIdx.x >> 6;
    int lane = threadIdx.x & 63;
    const float pr = prevr[0];
    if (blockIdx.x < 192) {
        int j = blockIdx.x * 4 + wave;  // 0..767
        float a0 = 0.f, a1 = 0.f, a2 = 0.f, a3 = 0.f;
        const float* r0 = Wih + (size_t)(0*H + j) * IN1;
        const float* r1 = Wih + (size_t)(1*H + j) * IN1;
        const float* r2 = Wih + (size_t)(2*H + j) * IN1;
        const float* r3 = Wih + (size_t)(3*H + j) * IN1;
        for (int k = lane; k < IN1; k += 64) {
            float xv = (k < ISZ) ? x[k] : pr;
            a0 += r0[k] * xv; a1 += r1[k] * xv; a2 += r2[k] * xv; a3 += r3[k] * xv;
        }
        const float* s0 = Whh + (size_t)(0*H + j) * H;
        const float* s1 = Whh + (size_t)(1*H + j) * H;
        const float* s2 = Whh + (size_t)(2*H + j) * H;
        const float* s3 = Whh + (size_t)(3*H + j) * H;
        for (int k = lane; k < H; k += 64) {
            float hv = h0[k];
            a0 += s0[k] * hv; a1 += s1[k] * hv; a2 += s2[k] * hv; a3 += s3[k] * hv;
        }
        a0 = wave_reduce(a0); a1 = wave_reduce(a1);
        a2 = wave_reduce(a2); a3 = wave_reduce(a3);
        if (lane == 0) {
            float zi = a0 + bih[0*H + j] + bhh[0*H + j];
            float zf = a1 + bih[1*H + j] + bhh[1*H + j];
            float zg = a2 + bih[2*H + j] + bhh[2*H + j];
            float zo = a3 + bih[3*H + j] + bhh[3*H + j];
            float ig = 1.f / (1.f + expf(-zi));
            float fg = 1.f / (1.f + expf(-zf));
            float gg = tanhf(zg);
            float og = 1.f / (1.f + expf(-zo));
            float cj = c0[j];
            float cn = fg * cj + ig * gg;
            float t  = tanhf(cn);
            float hn = og * t;
            float dtc = og * (1.f - t * t);
            ws[W_D + 0*H + j] = dtc * gg * ig * (1.f - ig);
            ws[W_D + 1*H + j] = dtc * cj * fg * (1.f - fg);
            ws[W_D + 2*H + j] = dtc * ig * (1.f - gg * gg);
            ws[W_D + 3*H + j] = t * og * (1.f - og);
            ws[W_HN + j] = hn;
            out[O_HN + j] = hn;
            out[O_CN + j] = cn;
        }
    } else {
        int r = (blockIdx.x - 192) * 4 + wave;  // 0..3071
        const float* uih = U + U_WIH + (size_t)r * IN1;
        const float* uhh = U + U_WHH + (size_t)r * H;
        float acc = 0.f;
        for (int k = lane; k < IN1; k += 64) {
            float xv = (k < ISZ) ? x[k] : pr;
            acc += xv * xv / uih[k];
        }
        for (int k = lane; k < H; k += 64) {
            float hv = h0[k];
            acc += hv * hv / uhh[k];
        }
        acc = wave_reduce(acc);
        if (lane == 0)
            ws[W_T + r] = acc + 1.f / U[U_BIH + r] + 1.f / U[U_BHH + r];
    }
}

// Kernel ARMS: one block per arm. Computes r, s (lstm part), q (fc row term).
__global__ __launch_bounds__(256) void k_arms(
    const float* __restrict__ fcW, const float* __restrict__ fcb,
    const float* __restrict__ U, float* __restrict__ ws)
{
    __shared__ float wsum_s[H];
    __shared__ float hn_s[H];
    __shared__ float part[3][4];
    int a = blockIdx.x;
    int t = threadIdx.x;
    for (int j = t; j < H; j += 256) {
        float d0 = ws[W_D + 0*H + j], T0 = ws[W_T + 0*H + j];
        float d1 = ws[W_D + 1*H + j], T1 = ws[W_T + 1*H + j];
        float d2 = ws[W_D + 2*H + j], T2 = ws[W_T + 2*H + j];
        float d3 = ws[W_D + 3*H + j], T3 = ws[W_T + 3*H + j];
        wsum_s[j] = d0*d0*T0 + d1*d1*T1 + d2*d2*T2 + d3*d3*T3;
        hn_s[j] = ws[W_HN + j];
    }
    __syncthreads();
    float ar = 0.f, as = 0.f, aq = 0.f;
    const float* frow = fcW + (size_t)a * H;
    const float* urow = U + U_FCW + (size_t)a * H;
    for (int j = t; j < H; j += 256) {
        float fw = frow[j], hv = hn_s[j];
        ar += fw * hv;
        as += fw * fw * wsum_s[j];
        aq += hv * hv / urow[j];
    }
    ar = wave_reduce(ar); as = wave_reduce(as); aq = wave_reduce(aq);
    int wave = t >> 6, lane = t & 63;
    if (lane == 0) { part[0][wave] = ar; part[1][wave] = as; part[2][wave] = aq; }
    __syncthreads();
    if (t == 0) {
        ws[W_R + a] = part[0][0] + part[0][1] + part[0][2] + part[0][3] + fcb[a];
        ws[W_S + a] = part[1][0] + part[1][1] + part[1][2] + part[1][3];
        ws[W_Q + a] = part[2][0] + part[2][1] + part[2][2] + part[2][3]
                      + 1.f / U[U_FCB + a];
    }
}

// Kernel FINAL: 1 block, 64 threads. Prefix-scan q, UCB argmax, softmax, outputs.
__global__ __launch_bounds__(64) void k_final(
    float* __restrict__ out, float* __restrict__ ws)
{
    int t = threadIdx.x;
    if (t < NARM) {
        float r = ws[W_R + t];
        float s = ws[W_S + t];
        float q = ws[W_Q + t];
        // inclusive prefix sum of q across 32 lanes
        float cum = q;
        for (int d = 1; d < 32; d <<= 1) {
            float v = __shfl_up(cum, d, 32);
            if (t >= d) cum += v;
        }
        float sc = r + NU_C * sqrtf(s + cum);
        // argmax (first max wins ties)
        float best = sc; int sel = t;
        for (int d = 16; d > 0; d >>= 1) {
            float ob = __shfl_xor(best, d, 32);
            int   oi = __shfl_xor(sel, d, 32);
            if (ob > best || (ob == best && oi < sel)) { best = ob; sel = oi; }
        }
        // softmax over r
        float mx = r;
        for (int d = 16; d > 0; d >>= 1) mx = fmaxf(mx, __shfl_xor(mx, d, 32));
        float e = expf(r - mx);
        float se = e;
        for (int d = 16; d > 0; d >>= 1) se += __shfl_xor(se, d, 32);
        out[O_PROB + t] = e / se;
        float rsel = __shfl(r, sel, 32);
        if (t == 0) {
            out[O_SELR] = rsel;
            out[O_SELA] = (float)sel;
            ((int*)ws)[W_SEL] = sel;
        }
    }
}

// Kernel E: U_new = U + G[sel]^2, region-wise. 6265 blocks x 256.
__global__ __launch_bounds__(256) void k_unew(
    const float* __restrict__ x, const float* __restrict__ prevr,
    const float* __restrict__ h0, const float* __restrict__ fcW,
    const float* __restrict__ U, float* __restrict__ out,
    const float* __restrict__ ws)
{
    const int sel = ((const int*)ws)[W_SEL];
    int b = blockIdx.x, t = threadIdx.x;
    float* Un = out + O_U;
    if (b < 3072) {               // W_ih rows
        int r = b;
        int g = r / H, j = r - g * H;
        float s = fcW[(size_t)sel * H + j] * ws[W_D + g*H + j];
        float s2 = s * s;
        const float pr = prevr[0];
        const float* u = U + U_WIH + (size_t)r * IN1;
        float* o = Un + U_WIH + (size_t)r * IN1;
        for (int k = t; k < IN1; k += 256) {
            float xv = (k < ISZ) ? x[k] : pr;
            o[k] = u[k] + s2 * xv * xv;
        }
    } else if (b < 6144) {        // W_hh rows
        int r = b - 3072;
        int g = r / H, j = r - g * H;
        float s = fcW[(size_t)sel * H + j] * ws[W_D + g*H + j];
        float s2 = s * s;
        const float* u = U + U_WHH + (size_t)r * H;
        float* o = Un + U_WHH + (size_t)r * H;
        for (int k = t; k < H; k += 256) {
            float hv = h0[k];
            o[k] = u[k] + s2 * hv * hv;
        }
    } else if (b < 6168) {        // biases (b_ih then b_hh, 6144 elems, 24 blocks)
        int m = (b - 6144) * 256 + t;      // 0..6143
        int r = (m < 3072) ? m : (m - 3072);
        int g = r / H, j = r - g * H;
        float s = fcW[(size_t)sel * H + j] * ws[W_D + g*H + j];
        int idx = U_BIH + m;
        Un[idx] = U[idx] + s * s;
    } else if (b < 6264) {        // fc_W (24576 elems, 96 blocks; 3 blocks per arm row)
        int bb = b - 6168;
        int a = bb / 3;
        int j = (bb - a * 3) * 256 + t;
        float hv = ws[W_HN + j];
        float add = (a <= sel) ? hv * hv : 0.f;
        int e = a * H + j;
        Un[U_FCW + e] = U[U_FCW + e] + add;
    } else {                      // fc_b (32 elems)
        if (t < NARM)
            Un[U_FCB + t] = U[U_FCB + t] + ((t <= sel) ? 1.f : 0.f);
    }
}

extern "C" void kernel_launch(void* const* d_in, const int* in_sizes, int n_in,
                              void* d_out, int out_size, void* d_ws, size_t ws_size,
                              hipStream_t stream) {
    const float* x     = (const float*)d_in[0];
    const float* prevr = (const float*)d_in[1];
    const float* h0    = (const float*)d_in[2];
    const float* c0    = (const float*)d_in[3];
    const float* Wih   = (const float*)d_in[4];
    const float* Whh   = (const float*)d_in[5];
    const float* bih   = (const float*)d_in[6];
    const float* bhh   = (const float*)d_in[7];
    const float* fcW   = (const float*)d_in[8];
    const float* fcb   = (const float*)d_in[9];
    const float* U     = (const float*)d_in[10];
    float* out = (float*)d_out;
    float* ws  = (float*)d_ws;

    hipLaunchKernelGGL(k_prep, dim3(960), dim3(256), 0, stream,
                       x, prevr, h0, c0, Wih, Whh, bih, bhh, U, out, ws);
    hipLaunchKernelGGL(k_arms, dim3(NARM), dim3(256), 0, stream,
                       fcW, fcb, U, ws);
    hipLaunchKernelGGL(k_final, dim3(1), dim3(64), 0, stream,
                       out, ws);
    hipLaunchKernelGGL(k_unew, dim3(6265), dim3(256), 0, stream,
                       x, prevr, h0, fcW, U, out, ws);
}

// Round 3
// 23.382 us; speedup vs baseline: 3.2197x; 1.3203x over previous
//
#include <hip/hip_runtime.h>
#include <math.h>

#define H 768
#define ISZ 512
#define IN1 513   // I+1
#define NARM 32
#define NU_C 0.1f

// U region offsets (elements)
#define U_WIH 0
#define U_WHH (3072*513)                 // 1575936
#define U_BIH (U_WHH + 3072*768)         // 3935232
#define U_BHH (U_BIH + 3072)             // 3938304
#define U_FCW (U_BHH + 3072)             // 3941376
#define U_FCB (U_FCW + 32*768)           // 3965952

// out offsets (elements)
#define O_SELR 0
#define O_PROB 1
#define O_SELA 33
#define O_HN   34
#define O_CN   (34+768)
#define O_U    (34+768+768)   // 1570

// ws layout (float units)
#define W_D    0        // 4*768 D factors (gate-major)
#define W_T    3072     // 3072 per-row U sums
#define W_HN   6144     // 768 h_new
#define W_SEL  6912     // int: selected arm
#define W_HZ   6913     // int: 1 if h0 has any nonzero

__device__ inline float wave_reduce(float v) {
    for (int d = 32; d > 0; d >>= 1) v += __shfl_xor(v, d, 64);
    return v;
}

__device__ inline float frcp(float x) { return __builtin_amdgcn_rcpf(x); }

__device__ inline void store_f4_as_2xf2(float* p, float4 v) {
    *(float2*)p = make_float2(v.x, v.y);
    *(float2*)(p + 2) = make_float2(v.z, v.w);
}

// K1: blocks 0..191 -> gates GEMV + activations + D factors (wave per j)
//     blocks 192..959 -> per-row reciprocal-U sums (wave per row)
// Whh / U_WHH segments are skipped entirely when h0 == 0 (runtime ballot).
__global__ __launch_bounds__(256) void k_prep(
    const float* __restrict__ x, const float* __restrict__ prevr,
    const float* __restrict__ h0, const float* __restrict__ c0,
    const float* __restrict__ Wih, const float* __restrict__ Whh,
    const float* __restrict__ bih, const float* __restrict__ bhh,
    const float* __restrict__ U,
    float* __restrict__ out, float* __restrict__ ws)
{
    int wave = threadIdx.x >> 6;
    int lane = threadIdx.x & 63;
    const float pr = prevr[0];

    // Each wave loads all of h0 as float4 (3 iters x 64 lanes x 4 = 768)
    float4 hv4[3];
    bool nzb = false;
    #pragma unroll
    for (int it = 0; it < 3; ++it) {
        hv4[it] = *(const float4*)(h0 + (lane + it * 64) * 4);
        nzb |= (hv4[it].x != 0.f) || (hv4[it].y != 0.f) ||
               (hv4[it].z != 0.f) || (hv4[it].w != 0.f);
    }
    const bool hnz = (__ballot(nzb) != 0ull);

    if (blockIdx.x < 192) {
        int j = blockIdx.x * 4 + wave;  // 0..767
        float a0 = 0.f, a1 = 0.f, a2 = 0.f, a3 = 0.f;
        const float* r0 = Wih + (size_t)(0*H + j) * IN1;
        const float* r1 = Wih + (size_t)(1*H + j) * IN1;
        const float* r2 = Wih + (size_t)(2*H + j) * IN1;
        const float* r3 = Wih + (size_t)(3*H + j) * IN1;
        for (int k = lane; k < IN1; k += 64) {
            float xv = (k < ISZ) ? x[k] : pr;
            a0 += r0[k] * xv; a1 += r1[k] * xv; a2 += r2[k] * xv; a3 += r3[k] * xv;
        }
        if (hnz) {
            const float* s0 = Whh + (size_t)(0*H + j) * H;
            const float* s1 = Whh + (size_t)(1*H + j) * H;
            const float* s2 = Whh + (size_t)(2*H + j) * H;
            const float* s3 = Whh + (size_t)(3*H + j) * H;
            #pragma unroll
            for (int it = 0; it < 3; ++it) {
                int c = (lane + it * 64) * 4;
                float4 h4 = hv4[it];
                float4 w;
                w = *(const float4*)(s0 + c);
                a0 += w.x*h4.x + w.y*h4.y + w.z*h4.z + w.w*h4.w;
                w = *(const float4*)(s1 + c);
                a1 += w.x*h4.x + w.y*h4.y + w.z*h4.z + w.w*h4.w;
                w = *(const float4*)(s2 + c);
                a2 += w.x*h4.x + w.y*h4.y + w.z*h4.z + w.w*h4.w;
                w = *(const float4*)(s3 + c);
                a3 += w.x*h4.x + w.y*h4.y + w.z*h4.z + w.w*h4.w;
            }
        }
        a0 = wave_reduce(a0); a1 = wave_reduce(a1);
        a2 = wave_reduce(a2); a3 = wave_reduce(a3);
        if (lane == 0) {
            float zi = a0 + bih[0*H + j] + bhh[0*H + j];
            float zf = a1 + bih[1*H + j] + bhh[1*H + j];
            float zg = a2 + bih[2*H + j] + bhh[2*H + j];
            float zo = a3 + bih[3*H + j] + bhh[3*H + j];
            float ig = 1.f / (1.f + expf(-zi));
            float fg = 1.f / (1.f + expf(-zf));
            float gg = tanhf(zg);
            float og = 1.f / (1.f + expf(-zo));
            float cj = c0[j];
            float cn = fg * cj + ig * gg;
            float t  = tanhf(cn);
            float hn = og * t;
            float dtc = og * (1.f - t * t);
            ws[W_D + 0*H + j] = dtc * gg * ig * (1.f - ig);
            ws[W_D + 1*H + j] = dtc * cj * fg * (1.f - fg);
            ws[W_D + 2*H + j] = dtc * ig * (1.f - gg * gg);
            ws[W_D + 3*H + j] = t * og * (1.f - og);
            ws[W_HN + j] = hn;
            out[O_HN + j] = hn;
            out[O_CN + j] = cn;
        }
    } else {
        int r = (blockIdx.x - 192) * 4 + wave;  // 0..3071
        const float* uih = U + U_WIH + (size_t)r * IN1;
        float acc = 0.f;
        for (int k = lane; k < IN1; k += 64) {
            float xv = (k < ISZ) ? x[k] : pr;
            acc += xv * xv * frcp(uih[k]);
        }
        if (hnz) {
            const float* uhh = U + U_WHH + (size_t)r * H;
            #pragma unroll
            for (int it = 0; it < 3; ++it) {
                int c = (lane + it * 64) * 4;
                float4 u4 = *(const float4*)(uhh + c);
                float4 h4 = hv4[it];
                acc += h4.x*h4.x*frcp(u4.x) + h4.y*h4.y*frcp(u4.y)
                     + h4.z*h4.z*frcp(u4.z) + h4.w*h4.w*frcp(u4.w);
            }
        }
        acc = wave_reduce(acc);
        if (lane == 0)
            ws[W_T + r] = acc + frcp(U[U_BIH + r]) + frcp(U[U_BHH + r]);
    }
}

// K2: fused arms + final. 1 block x 1024 threads (16 waves, 2 arms each).
__global__ __launch_bounds__(1024) void k_armsfinal(
    const float* __restrict__ fcW, const float* __restrict__ fcb,
    const float* __restrict__ h0, const float* __restrict__ U,
    float* __restrict__ out, float* __restrict__ ws)
{
    __shared__ float wsum_s[H];
    __shared__ float hn_s[H];
    __shared__ float r_s[NARM], s_s[NARM], q_s[NARM];
    __shared__ int nzflag;
    int t = threadIdx.x;
    if (t == 0) nzflag = 0;
    __syncthreads();
    if (t < H) {
        float d0 = ws[W_D + 0*H + t], T0 = ws[W_T + 0*H + t];
        float d1 = ws[W_D + 1*H + t], T1 = ws[W_T + 1*H + t];
        float d2 = ws[W_D + 2*H + t], T2 = ws[W_T + 2*H + t];
        float d3 = ws[W_D + 3*H + t], T3 = ws[W_T + 3*H + t];
        wsum_s[t] = d0*d0*T0 + d1*d1*T1 + d2*d2*T2 + d3*d3*T3;
        hn_s[t] = ws[W_HN + t];
        if (h0[t] != 0.f) atomicOr(&nzflag, 1);
    }
    __syncthreads();
    int wave = t >> 6, lane = t & 63;
    for (int a = wave; a < NARM; a += 16) {
        const float* frow = fcW + (size_t)a * H;
        const float* urow = U + U_FCW + (size_t)a * H;
        float ar = 0.f, as = 0.f, aq = 0.f;
        #pragma unroll
        for (int it = 0; it < 3; ++it) {
            int j = lane * 4 + it * 256;
            float4 f4 = *(const float4*)(frow + j);
            float4 u4 = *(const float4*)(urow + j);
            float4 h4 = *(const float4*)(&hn_s[j]);
            float4 w4 = *(const float4*)(&wsum_s[j]);
            ar += f4.x*h4.x + f4.y*h4.y + f4.z*h4.z + f4.w*h4.w;
            as += f4.x*f4.x*w4.x + f4.y*f4.y*w4.y + f4.z*f4.z*w4.z + f4.w*f4.w*w4.w;
            aq += h4.x*h4.x*frcp(u4.x) + h4.y*h4.y*frcp(u4.y)
                + h4.z*h4.z*frcp(u4.z) + h4.w*h4.w*frcp(u4.w);
        }
        ar = wave_reduce(ar); as = wave_reduce(as); aq = wave_reduce(aq);
        if (lane == 0) {
            r_s[a] = ar + fcb[a];
            s_s[a] = as;
            q_s[a] = aq + frcp(U[U_FCB + a]);
        }
    }
    __syncthreads();
    if (t == 0) ((int*)ws)[W_HZ] = nzflag;
    if (t < NARM) {
        float r = r_s[t];
        float s = s_s[t];
        float q = q_s[t];
        // inclusive prefix sum of q across 32 lanes
        float cum = q;
        for (int d = 1; d < 32; d <<= 1) {
            float v = __shfl_up(cum, d, 32);
            if (t >= d) cum += v;
        }
        float sc = r + NU_C * sqrtf(s + cum);
        // argmax (first max wins ties)
        float best = sc; int sel = t;
        for (int d = 16; d > 0; d >>= 1) {
            float ob = __shfl_xor(best, d, 32);
            int   oi = __shfl_xor(sel, d, 32);
            if (ob > best || (ob == best && oi < sel)) { best = ob; sel = oi; }
        }
        // softmax over r
        float mx = r;
        for (int d = 16; d > 0; d >>= 1) mx = fmaxf(mx, __shfl_xor(mx, d, 32));
        float e = expf(r - mx);
        float se = e;
        for (int d = 16; d > 0; d >>= 1) se += __shfl_xor(se, d, 32);
        out[O_PROB + t] = e / se;
        float rsel = __shfl(r, sel, 32);
        if (t == 0) {
            out[O_SELR] = rsel;
            out[O_SELA] = (float)sel;
            ((int*)ws)[W_SEL] = sel;
        }
    }
}

// K3: U_new = U + G[sel]^2, region-wise.
// grid: [0,3072) W_ih rows | [3072,5376) W_hh flat f4 | 6 bias blocks |
//       24 fcW blocks | 1 fcb block  => 5407 blocks
#define B_A 3072
#define B_B (B_A + 2304)
#define B_C (B_B + 6)
#define B_D (B_C + 24)
__global__ __launch_bounds__(256) void k_unew(
    const float* __restrict__ x, const float* __restrict__ prevr,
    const float* __restrict__ h0, const float* __restrict__ fcW,
    const float* __restrict__ U, float* __restrict__ out,
    const float* __restrict__ ws)
{
    const int sel = ((const int*)ws)[W_SEL];
    const int hnz = ((const int*)ws)[W_HZ];
    int b = blockIdx.x, t = threadIdx.x;
    float* Un = out + O_U;
    if (b < B_A) {                 // W_ih rows, one row per block (513 elems)
        int g = b / H, j = b - g * H;
        float s = fcW[(size_t)sel * H + j] * ws[W_D + g*H + j];
        float s2 = s * s;
        const float* u = U + U_WIH + (size_t)b * IN1;
        float* o = Un + U_WIH + (size_t)b * IN1;
        float xv1 = x[t];
        float xv2 = x[t + 256];
        o[t]       = u[t]       + s2 * xv1 * xv1;
        o[t + 256] = u[t + 256] + s2 * xv2 * xv2;
        if (t == 0) {
            float pr = prevr[0];
            o[512] = u[512] + s2 * pr * pr;
        }
    } else if (b < B_B) {          // W_hh flat float4 (copy when h0==0)
        int i4 = (b - B_A) * 256 + t;
        int e = i4 * 4;            // < 2359296
        float4 u4 = *(const float4*)(U + U_WHH + e);
        float4 o4;
        if (hnz) {
            int r = e / H;
            int g = r / H, j = r - g * H;
            int k = e - r * H;
            float s = fcW[(size_t)sel * H + j] * ws[W_D + g*H + j];
            float s2 = s * s;
            float4 h4 = *(const float4*)(h0 + k);
            o4.x = u4.x + s2 * h4.x * h4.x;
            o4.y = u4.y + s2 * h4.y * h4.y;
            o4.z = u4.z + s2 * h4.z * h4.z;
            o4.w = u4.w + s2 * h4.w * h4.w;
        } else {
            o4 = u4;
        }
        store_f4_as_2xf2(Un + U_WHH + e, o4);
    } else if (b < B_C) {          // biases: 6144 elems, float4
        int m = ((b - B_B) * 256 + t) * 4;
        int r = (m < 3072) ? m : m - 3072;
        int g = r / H, j = r - g * H;
        float4 f4 = *(const float4*)(fcW + (size_t)sel * H + j);
        float4 d4 = *(const float4*)(ws + W_D + g*H + j);
        float4 u4 = *(const float4*)(U + U_BIH + m);
        float4 o4;
        float sx = f4.x*d4.x, sy = f4.y*d4.y, sz = f4.z*d4.z, sw = f4.w*d4.w;
        o4.x = u4.x + sx*sx; o4.y = u4.y + sy*sy;
        o4.z = u4.z + sz*sz; o4.w = u4.w + sw*sw;
        store_f4_as_2xf2(Un + U_BIH + m, o4);
    } else if (b < B_D) {          // fc_W: 24576 elems, float4
        int e = ((b - B_C) * 256 + t) * 4;
        int a = e / H, j = e - a * H;
        float4 h4 = *(const float4*)(ws + W_HN + j);
        float4 u4 = *(const float4*)(U + U_FCW + e);
        float m = (a <= sel) ? 1.f : 0.f;
        float4 o4;
        o4.x = u4.x + m * h4.x * h4.x;
        o4.y = u4.y + m * h4.y * h4.y;
        o4.z = u4.z + m * h4.z * h4.z;
        o4.w = u4.w + m * h4.w * h4.w;
        store_f4_as_2xf2(Un + U_FCW + e, o4);
    } else {                       // fc_b
        if (t < NARM)
            Un[U_FCB + t] = U[U_FCB + t] + ((t <= sel) ? 1.f : 0.f);
    }
}

extern "C" void kernel_launch(void* const* d_in, const int* in_sizes, int n_in,
                              void* d_out, int out_size, void* d_ws, size_t ws_size,
                              hipStream_t stream) {
    const float* x     = (const float*)d_in[0];
    const float* prevr = (const float*)d_in[1];
    const float* h0    = (const float*)d_in[2];
    const float* c0    = (const float*)d_in[3];
    const float* Wih   = (const float*)d_in[4];
    const float* Whh   = (const float*)d_in[5];
    const float* bih   = (const float*)d_in[6];
    const float* bhh   = (const float*)d_in[7];
    const float* fcW   = (const float*)d_in[8];
    const float* fcb   = (const float*)d_in[9];
    const float* U     = (const float*)d_in[10];
    float* out = (float*)d_out;
    float* ws  = (float*)d_ws;

    hipLaunchKernelGGL(k_prep, dim3(960), dim3(256), 0, stream,
                       x, prevr, h0, c0, Wih, Whh, bih, bhh, U, out, ws);
    hipLaunchKernelGGL(k_armsfinal, dim3(1), dim3(1024), 0, stream,
                       fcW, fcb, h0, U, out, ws);
    hipLaunchKernelGGL(k_unew, dim3(B_D + 1), dim3(256), 0, stream,
                       x, prevr, h0, fcW, U, out, ws);
}